// Round 2
// baseline (168.445 us; speedup 1.0000x reference)
//
#include <hip/hip_runtime.h>
#include <hip/hip_bf16.h>

// Qu mutual-information circuit: N_QUBITS=12, 1 layer, DIM=4096, SUB_DIM=64.
//
// Math reduction (vs reference's dense 4096x4096 U rho U^H):
//   L = LA (x) LB   (kron of per-qubit 2x2 gates; LA,LB are 64x64)
//   U = L P L       (P = CNOT permutation, row-gather: L[perm,:] = P L)
//   Tr_B(U (X1(x)X2) U^H) = LA * T * LA^H
//     where A1 = LA X1 LA^H, B1 = LB X2 LB^H,
//           T[pA,qA] = sum_k A1[pr>>6, qr>>6] * B1[pr&63, qr&63],
//           pr = perm[pA*64+k], qr = perm[qA*64+k]
//   (outer LB disappears: sum_k LB[k,pB] conj(LB[k,qB]) = delta under the trace)
//
// One fused kernel, 4 blocks = (order in {BatA, AatB}) x (batch in {0,1}).
// All intermediates live in LDS (~148 KB). No workspace used.
//
// OUTPUT FORMAT is selected at runtime from out_size:
//   16384 -> float32, REAL PARTS ONLY  (complex64 -> astype(float32) conversion)
//   32768 -> bf16, interleaved re/im   (complex64 -> f32 pairs -> bf16)
//   else  -> float32 interleaved re/im

#define W_MUL 0.6324555320336759f   // sqrt(2)/sqrt(5)

__device__ __forceinline__ float2 cmul(float2 a, float2 b) {
    return make_float2(a.x * b.x - a.y * b.y, a.x * b.y + a.y * b.x);
}
__device__ __forceinline__ float2 cfma(float2 a, float2 b, float2 c) {
    c.x = fmaf(a.x, b.x, fmaf(-a.y, b.y, c.x));
    c.y = fmaf(a.x, b.y, fmaf(a.y, b.x, c.y));
    return c;
}
__device__ __forceinline__ float2 conjc(float2 a) { return make_float2(a.x, -a.y); }

// Composite CNOT-chain permutation for 12 qubits, 1 layer.
// gates (forward): (0,1),(1,2),...,(10,11),(11,0); reference applies reversed.
__device__ __forceinline__ int cnot_perm(int p) {
    p ^= ((p >> 0) & 1) << 11;                    // gate (11,0): bc=0, bt=11
    #pragma unroll
    for (int q = 10; q >= 0; --q) {               // gates (q,q+1): bc=11-q, bt=10-q
        p ^= ((p >> (11 - q)) & 1) << (10 - q);
    }
    return p;
}

// G_q = Rz(tz) @ Ry(ty) @ Rx(tx), 2x2 complex.
__device__ __forceinline__ void make_G(const float* w, int q, float2 G[2][2]) {
    float tx = w[q]      * (W_MUL * 0.5f);
    float ty = w[12 + q] * (W_MUL * 0.5f);
    float tz = w[24 + q] * (W_MUL * 0.5f);
    float cx, sx, cy, sy, cz, sz;
    sincosf(tx, &sx, &cx);
    sincosf(ty, &sy, &cy);
    sincosf(tz, &sz, &cz);
    // M = Ry@Rx
    float2 M00 = make_float2( cy * cx,  sy * sx);
    float2 M01 = make_float2(-sy * cx, -cy * sx);
    float2 M10 = make_float2( sy * cx, -cy * sx);
    float2 M11 = make_float2( cy * cx, -sy * sx);
    float2 ez  = make_float2(cz, -sz);   // e^{-i tz/2}
    float2 ezc = make_float2(cz,  sz);
    G[0][0] = cmul(ez,  M00);
    G[0][1] = cmul(ez,  M01);
    G[1][0] = cmul(ezc, M10);
    G[1][1] = cmul(ezc, M11);
}

// Build conj-transpose of L = kron(G[0..5]) into dst: dst[k*64+i] = conj(L[i][k]).
__device__ __forceinline__ void build_LH(const float2 G6[6][2][2], float2* dst, int tid) {
    for (int e = tid; e < 4096; e += 1024) {
        int i = e >> 6, j = e & 63;
        float2 p = G6[0][(i >> 5) & 1][(j >> 5) & 1];
        p = cmul(p, G6[1][(i >> 4) & 1][(j >> 4) & 1]);
        p = cmul(p, G6[2][(i >> 3) & 1][(j >> 3) & 1]);
        p = cmul(p, G6[3][(i >> 2) & 1][(j >> 2) & 1]);
        p = cmul(p, G6[4][(i >> 1) & 1][(j >> 1) & 1]);
        p = cmul(p, G6[5][(i     ) & 1][(j     ) & 1]);
        dst[j * 64 + i] = conjc(p);   // LH[j][i] = conj(L[i][j])
    }
}

// OM: 0 = f32 real-only, 1 = bf16 interleaved, 2 = f32 interleaved
template <int OM>
__global__ __launch_bounds__(1024) void qmutual_kernel(
    const float* __restrict__ A, const float* __restrict__ B,
    const float* __restrict__ w, void* __restrict__ outv)
{
    __shared__ float2 buf0[4096];   // LAH -> LBH -> T
    __shared__ float2 buf1[4096];   // TMP1 -> TMP2 -> LAH(rebuilt)
    __shared__ float2 buf2[4096];   // A1
    __shared__ float2 buf3[4096];   // B1 -> TMPfinal
    __shared__ float  Xr[4096];     // real input tile; later perm (ushort) aliases it
    __shared__ float2 G6[6][2][2];

    const int m = blockIdx.x;
    const int order = m >> 1;       // 0: mutualBatA (rho = A(x)B), 1: mutualAatB
    const int b = m & 1;
    const int tid = threadIdx.x;

    const float* X1g = (order == 0 ? A : B) + b * 4096;  // LA-side factor (retained)
    const float* X2g = (order == 0 ? B : A) + b * 4096;  // LB-side factor (traced out)

    // ---- Phase 0: G(qubits 0..5); LAH -> buf0; X1 -> Xr ----
    if (tid < 6) make_G(w, tid, G6[tid]);
    __syncthreads();
    build_LH(G6, buf0, tid);
    for (int e = tid; e < 4096; e += 1024) Xr[e] = X1g[e];
    __syncthreads();

    // ---- Phase 1: buf1 = LA @ X1   (L[i][k] = conj(buf0[k*64+i]), X real) ----
    for (int e = tid; e < 4096; e += 1024) {
        int i = e >> 6, j = e & 63;
        float ax = 0.f, ay = 0.f;
        #pragma unroll 8
        for (int k = 0; k < 64; ++k) {
            float2 lh = buf0[k * 64 + i];
            float  x  = Xr[k * 64 + j];
            ax = fmaf(lh.x, x, ax);
            ay = fmaf(-lh.y, x, ay);
        }
        buf1[e] = make_float2(ax, ay);
    }
    __syncthreads();

    // ---- Phase 2: buf2 = A1 = TMP @ LA^H ----
    for (int e = tid; e < 4096; e += 1024) {
        int i = e >> 6, j = e & 63;
        float2 acc = make_float2(0.f, 0.f);
        #pragma unroll 8
        for (int k = 0; k < 64; ++k)
            acc = cfma(buf1[i * 64 + k], buf0[k * 64 + j], acc);
        buf2[e] = acc;
    }
    __syncthreads();

    // ---- Phase 3: G(qubits 6..11); LBH -> buf0; X2 -> Xr ----
    if (tid < 6) make_G(w, 6 + tid, G6[tid]);
    __syncthreads();
    build_LH(G6, buf0, tid);
    for (int e = tid; e < 4096; e += 1024) Xr[e] = X2g[e];
    __syncthreads();

    // ---- Phase 4: buf1 = LB @ X2 ----
    for (int e = tid; e < 4096; e += 1024) {
        int i = e >> 6, j = e & 63;
        float ax = 0.f, ay = 0.f;
        #pragma unroll 8
        for (int k = 0; k < 64; ++k) {
            float2 lh = buf0[k * 64 + i];
            float  x  = Xr[k * 64 + j];
            ax = fmaf(lh.x, x, ax);
            ay = fmaf(-lh.y, x, ay);
        }
        buf1[e] = make_float2(ax, ay);
    }
    __syncthreads();

    // ---- Phase 5: buf3 = B1 = TMP2 @ LB^H ----
    for (int e = tid; e < 4096; e += 1024) {
        int i = e >> 6, j = e & 63;
        float2 acc = make_float2(0.f, 0.f);
        #pragma unroll 8
        for (int k = 0; k < 64; ++k)
            acc = cfma(buf1[i * 64 + k], buf0[k * 64 + j], acc);
        buf3[e] = acc;
    }
    __syncthreads();

    // ---- Phase 6a: perm table into Xr (as ushort) ----
    unsigned short* perm = (unsigned short*)Xr;
    for (int e = tid; e < 4096; e += 1024) perm[e] = (unsigned short)cnot_perm(e);
    __syncthreads();

    // ---- Phase 6b: T -> buf0.  T[pA][qA] = sum_k A1[pr>>6][qr>>6]*B1[pr&63][qr&63] ----
    for (int e = tid; e < 4096; e += 1024) {
        int pA = e >> 6, qA = e & 63;
        int pbase = pA << 6, qbase = qA << 6;
        float2 acc = make_float2(0.f, 0.f);
        #pragma unroll 4
        for (int k = 0; k < 64; ++k) {
            int pr = perm[pbase + k];
            int qr = perm[qbase + k];
            float2 a1 = buf2[((pr >> 6) << 6) | (qr >> 6)];
            float2 b1 = buf3[((pr & 63) << 6) | (qr & 63)];
            acc = cfma(a1, b1, acc);
        }
        buf0[e] = acc;
    }
    __syncthreads();

    // ---- Phase 7: rebuild G(0..5), LAH -> buf1 ----
    if (tid < 6) make_G(w, tid, G6[tid]);
    __syncthreads();
    build_LH(G6, buf1, tid);
    __syncthreads();

    // ---- Phase 8: buf3 = LA @ T ----
    for (int e = tid; e < 4096; e += 1024) {
        int i = e >> 6, j = e & 63;
        float2 acc = make_float2(0.f, 0.f);
        #pragma unroll 8
        for (int k = 0; k < 64; ++k) {
            float2 lh = buf1[k * 64 + i];   // conj(LA[i][k])
            float2 t  = buf0[k * 64 + j];
            acc.x = fmaf(lh.x, t.x, fmaf( lh.y, t.y, acc.x));
            acc.y = fmaf(lh.x, t.y, fmaf(-lh.y, t.x, acc.y));
        }
        buf3[e] = acc;
    }
    __syncthreads();

    // ---- Phase 9: OUT = TMPf @ LA^H -> global, format per OM ----
    for (int e = tid; e < 4096; e += 1024) {
        int i = e >> 6, j = e & 63;
        float2 acc = make_float2(0.f, 0.f);
        #pragma unroll 8
        for (int k = 0; k < 64; ++k)
            acc = cfma(buf3[i * 64 + k], buf1[k * 64 + j], acc);
        if constexpr (OM == 0) {
            float* og = (float*)outv + (order * 2 + b) * 4096;
            og[e] = acc.x;                       // real part only
        } else if constexpr (OM == 1) {
            __hip_bfloat16* og = (__hip_bfloat16*)outv + (order * 2 + b) * 8192;
            og[2 * e]     = __float2bfloat16(acc.x);
            og[2 * e + 1] = __float2bfloat16(acc.y);
        } else {
            float2* og = (float2*)outv + (order * 2 + b) * 4096;
            og[e] = acc;
        }
    }
}

extern "C" void kernel_launch(void* const* d_in, const int* in_sizes, int n_in,
                              void* d_out, int out_size, void* d_ws, size_t ws_size,
                              hipStream_t stream) {
    const float* A = (const float*)d_in[0];   // (2,64,64) f32
    const float* B = (const float*)d_in[1];   // (2,64,64) f32
    const float* w = (const float*)d_in[2];   // (72,) f32
    (void)in_sizes; (void)n_in; (void)d_ws; (void)ws_size;
    if (out_size == 16384) {
        // complex64 -> float32 real-parts-only conversion
        qmutual_kernel<0><<<4, 1024, 0, stream>>>(A, B, w, d_out);
    } else if (out_size == 32768) {
        // complex64 -> f32 pairs -> bf16 interleaved
        qmutual_kernel<1><<<4, 1024, 0, stream>>>(A, B, w, d_out);
    } else {
        qmutual_kernel<2><<<4, 1024, 0, stream>>>(A, B, w, d_out);
    }
}

// Round 3
// 81.689 us; speedup vs baseline: 2.0620x; 2.0620x over previous
//
#include <hip/hip_runtime.h>
#include <hip/hip_bf16.h>

// Qu mutual-information circuit: N_QUBITS=12, DIM=4096, SUB_DIM=64, 1 layer.
//
// Full reduction:
//   L = LA (x) LB,  U = L P L,  Tr_B(U (X1(x)X2) U^H) = LA * T * LA^H
//   P is GF(2)-linear: perm(pA*64+k) = perm(pA<<6) ^ perm(k).
//   A-row of perm(p*64+k) = g(p) ^ (k0*48),  g(p) = p ^ (p>>1) (Gray code)
//   B-row = h(k) ^ (p0*32), h bijective with parity(h(k)) = k0.
//   => T[p,q] = A1[u,v]*W0(p0,q0) + A1[u^48,v^48]*W1(p0,q0),  u=g(p), v=g(q)
//      with W's from 4 scalars: e_p = sum_{par m = p} B1[m,m],
//                               f_p = sum_{par m = p} B1[m,m^32]
//      and  W_p[0][0]=e_p, W_p[1][1]=e_{1-p}, W_p[0][1]=f_p, W_p[1][0]=f_{1-p}.
//   e/f via operator traces (LB^H O LB = kron of 2x2s, unitarity kills I factors):
//      e0+e1 = Tr(X2);             e0-e1 = Tr(X2 * kron_q(Gq^H Z Gq))
//      f0+f1 = Tr(X2 * (G6^H X G6)(x)I^5)
//      f0-f1 = Tr(X2 * (G6^H XZ G6)(x)kron_{q=7..11}(Gq^H Z Gq))
//   => LB-side GEMMs eliminated entirely.
//
// K1 (20 blocks x 512): 16 blocks = A1[X] (4 inputs x 4 row-quarters, 2 GEMMs
// each with 2-wide register tiles, <=2-way LDS banking); 4 blocks = trace quads.
// K2 (16 blocks x 512): evolution x row-quarter: form T, R = LA*T*LA^H -> out.
// Mono fallback (4 blocks x 1024) if ws_size < 131200 B.

#define W_MUL 0.6324555320336759f   // sqrt(2)/sqrt(5)

__device__ __forceinline__ float2 cmul(float2 a, float2 b) {
    return make_float2(a.x * b.x - a.y * b.y, a.x * b.y + a.y * b.x);
}
__device__ __forceinline__ float2 cadd(float2 a, float2 b) { return make_float2(a.x + b.x, a.y + b.y); }
__device__ __forceinline__ float2 csub(float2 a, float2 b) { return make_float2(a.x - b.x, a.y - b.y); }
__device__ __forceinline__ float2 conjc(float2 a) { return make_float2(a.x, -a.y); }
// c += a*b
__device__ __forceinline__ float2 cfma(float2 a, float2 b, float2 c) {
    c.x = fmaf(a.x, b.x, fmaf(-a.y, b.y, c.x));
    c.y = fmaf(a.x, b.y, fmaf( a.y, b.x, c.y));
    return c;
}
// c += conj(a)*b
__device__ __forceinline__ float2 cfmac(float2 a, float2 b, float2 c) {
    c.x = fmaf(a.x, b.x, fmaf( a.y, b.y, c.x));
    c.y = fmaf(a.x, b.y, fmaf(-a.y, b.x, c.y));
    return c;
}

// G_q = Rz(tz) @ Ry(ty) @ Rx(tx), 2x2 complex.
__device__ __forceinline__ void make_G(const float* w, int q, float2 G[2][2]) {
    float tx = w[q]      * (W_MUL * 0.5f);
    float ty = w[12 + q] * (W_MUL * 0.5f);
    float tz = w[24 + q] * (W_MUL * 0.5f);
    float cx, sx, cy, sy, cz, sz;
    sincosf(tx, &sx, &cx);
    sincosf(ty, &sy, &cy);
    sincosf(tz, &sz, &cz);
    float2 M00 = make_float2( cy * cx,  sy * sx);
    float2 M01 = make_float2(-sy * cx, -cy * sx);
    float2 M10 = make_float2( sy * cx, -cy * sx);
    float2 M11 = make_float2( cy * cx, -sy * sx);
    float2 ez  = make_float2(cz, -sz);
    float2 ezc = make_float2(cz,  sz);
    G[0][0] = cmul(ez,  M00);
    G[0][1] = cmul(ez,  M01);
    G[1][0] = cmul(ezc, M10);
    G[1][1] = cmul(ezc, M11);
}

// dst[k*64+i] = conj(L[i][k]) for L = kron(G[0..5]).
__device__ __forceinline__ void build_LH(const float2 G[6][2][2], float2* dst, int t, int nt) {
    for (int e = t; e < 4096; e += nt) {
        int i = e >> 6, j = e & 63;
        float2 p = G[0][(i >> 5) & 1][(j >> 5) & 1];
        p = cmul(p, G[1][(i >> 4) & 1][(j >> 4) & 1]);
        p = cmul(p, G[2][(i >> 3) & 1][(j >> 3) & 1]);
        p = cmul(p, G[3][(i >> 2) & 1][(j >> 2) & 1]);
        p = cmul(p, G[4][(i >> 1) & 1][(j >> 1) & 1]);
        p = cmul(p, G[5][(i     ) & 1][(j     ) & 1]);
        dst[j * 64 + i] = conjc(p);
    }
}

// 2x2 trace tables from G (qubits 6..11): zt[q] = Gq^H Z Gq; x6 = G6^H X G6; xz6 = G6^H (XZ) G6.
__device__ __forceinline__ void make_tables(const float2 G[6][2][2],
                                            float2 zt[6][2][2], float2 x6[2][2], float2 xz6[2][2]) {
    #pragma unroll
    for (int q = 0; q < 6; ++q)
        #pragma unroll
        for (int a = 0; a < 2; ++a)
            #pragma unroll
            for (int b = 0; b < 2; ++b) {
                float2 g0a = G[q][0][a], g0b = G[q][0][b];
                float2 g1a = G[q][1][a], g1b = G[q][1][b];
                zt[q][a][b] = csub(cmul(conjc(g0a), g0b), cmul(conjc(g1a), g1b));
                if (q == 0) {
                    x6[a][b]  = cadd(cmul(conjc(g0a), g1b), cmul(conjc(g1a), g0b));
                    xz6[a][b] = csub(cmul(conjc(g1a), g0b), cmul(conjc(g0a), g1b));
                }
            }
}

// Per-thread trace partials: acc = {tz.x,tz.y, txz.x,txz.y, tx.x,tx.y, t0}
__device__ __forceinline__ void trace_acc(const float* Xr, const float2 zt[6][2][2],
                                          const float2 x6[2][2], const float2 xz6[2][2],
                                          int t, int nt, float acc[7]) {
    for (int e = t; e < 4096; e += nt) {
        int r = e >> 6, c = e & 63;       // term X2[r][c] * K[c][r]
        float xv = Xr[e];
        float2 P = zt[1][(c >> 4) & 1][(r >> 4) & 1];
        P = cmul(P, zt[2][(c >> 3) & 1][(r >> 3) & 1]);
        P = cmul(P, zt[3][(c >> 2) & 1][(r >> 2) & 1]);
        P = cmul(P, zt[4][(c >> 1) & 1][(r >> 1) & 1]);
        P = cmul(P, zt[5][c & 1][r & 1]);
        float2 pz  = cmul(zt[0][c >> 5][r >> 5], P);
        float2 pxz = cmul(xz6[c >> 5][r >> 5], P);
        acc[0] = fmaf(pz.x,  xv, acc[0]); acc[1] = fmaf(pz.y,  xv, acc[1]);
        acc[2] = fmaf(pxz.x, xv, acc[2]); acc[3] = fmaf(pxz.y, xv, acc[3]);
        if ((c & 31) == (r & 31)) {
            float2 kx = x6[c >> 5][r >> 5];
            acc[4] = fmaf(kx.x, xv, acc[4]); acc[5] = fmaf(kx.y, xv, acc[5]);
            if (c == r) acc[6] += xv;
        }
    }
}

// Reduce acc[7] across the block; returns true on thread 0 with totals in acc.
template <int NT>
__device__ __forceinline__ bool reduce7(float acc[7], float (*red)[8], int t) {
    #pragma unroll
    for (int o = 32; o; o >>= 1)
        #pragma unroll
        for (int m = 0; m < 7; ++m) acc[m] += __shfl_down(acc[m], o);
    if ((t & 63) == 0)
        for (int m = 0; m < 7; ++m) red[t >> 6][m] = acc[m];
    __syncthreads();
    if (t == 0) {
        for (int m = 0; m < 7; ++m) {
            float s = 0.f;
            for (int wv = 0; wv < NT / 64; ++wv) s += red[wv][m];
            acc[m] = s;
        }
        return true;
    }
    return false;
}

// T coefficients by (p&1, q&1)
__device__ __forceinline__ void pick_cc(int p, int q, float2 e0, float2 e1, float2 f0, float2 f1,
                                        float2& c0, float2& c1) {
    if (p & 1) { if (q & 1) { c0 = e1; c1 = e0; } else { c0 = f1; c1 = f0; } }
    else       { if (q & 1) { c0 = f0; c1 = f1; } else { c0 = e0; c1 = e1; } }
}

template <int OM>
__device__ __forceinline__ void write_out(void* outv, int ev, int i, int tc, float2 r0, float2 r1) {
    if constexpr (OM == 0) {
        float* og = (float*)outv + (ev << 12) + (i << 6);
        og[tc] = r0.x; og[tc + 32] = r1.x;
    } else if constexpr (OM == 1) {
        __hip_bfloat16* og = (__hip_bfloat16*)outv + (ev << 13) + (i << 7);
        og[2 * tc]      = __float2bfloat16(r0.x); og[2 * tc + 1]  = __float2bfloat16(r0.y);
        og[2 * tc + 64] = __float2bfloat16(r1.x); og[2 * tc + 65] = __float2bfloat16(r1.y);
    } else {
        float2* og = (float2*)outv + (ev << 12) + (i << 6);
        og[tc] = r0; og[tc + 32] = r1;
    }
}

// ---------------- K1: A1[X] (blocks 0..15) + trace quads (blocks 16..19) ----------------
__global__ __launch_bounds__(512) void qk1(const float* __restrict__ A, const float* __restrict__ B,
                                           const float* __restrict__ w, float2* __restrict__ ws) {
    __shared__ float2 LAH[4096];
    __shared__ float  Xr[4096];
    __shared__ float2 TMP[1024];
    __shared__ float2 G6[6][2][2];
    __shared__ float  red[8][8];

    const int bx = blockIdx.x;
    const int t  = threadIdx.x;

    if (bx < 16) {
        const int x  = bx >> 2;               // 0:A0 1:A1 2:B0 3:B1
        const int I0 = (bx & 3) << 4;
        const float* Xg = (x < 2) ? (A + x * 4096) : (B + (x - 2) * 4096);
        if (t < 6) make_G(w, t, G6[t]);
        __syncthreads();
        build_LH(G6, LAH, t, 512);
        for (int e = t; e < 4096; e += 512) Xr[e] = Xg[e];
        __syncthreads();

        const int tr = t >> 5, tc = t & 31;
        const int i  = I0 + tr;
        // GEMM1: TMP[tr][j] = sum_k conj(LAH[k*64+i]) * X[k][j]   (LA @ X, X real)
        float2 a0 = make_float2(0, 0), a1 = make_float2(0, 0);
        #pragma unroll 16
        for (int k = 0; k < 64; ++k) {
            float2 la = LAH[(k << 6) + i];          // broadcast within wave
            float x0 = Xr[(k << 6) + tc], x1 = Xr[(k << 6) + tc + 32];
            a0.x = fmaf(la.x, x0, a0.x); a0.y = fmaf(-la.y, x0, a0.y);
            a1.x = fmaf(la.x, x1, a1.x); a1.y = fmaf(-la.y, x1, a1.y);
        }
        TMP[(tr << 6) + tc] = a0; TMP[(tr << 6) + tc + 32] = a1;
        __syncthreads();
        // GEMM2: A1[i][j] = sum_k TMP[tr][k] * LAH[k*64+j]
        float2 c0 = make_float2(0, 0), c1 = make_float2(0, 0);
        #pragma unroll 16
        for (int k = 0; k < 64; ++k) {
            float2 tm = TMP[(tr << 6) + k];         // broadcast
            float2 l0 = LAH[(k << 6) + tc], l1 = LAH[(k << 6) + tc + 32];
            c0 = cfma(tm, l0, c0); c1 = cfma(tm, l1, c1);
        }
        ws[(x << 12) + (i << 6) + tc]      = c0;
        ws[(x << 12) + (i << 6) + tc + 32] = c1;
    } else {
        const int x = bx - 16;
        const float* Xg = (x < 2) ? (A + x * 4096) : (B + (x - 2) * 4096);
        if (t < 6) make_G(w, 6 + t, G6[t]);
        for (int e = t; e < 4096; e += 512) Xr[e] = Xg[e];
        __syncthreads();
        float2 zt[6][2][2], x6[2][2], xz6[2][2];
        make_tables(G6, zt, x6, xz6);
        float acc[7] = {0, 0, 0, 0, 0, 0, 0};
        trace_acc(Xr, zt, x6, xz6, t, 512, acc);
        if (reduce7<512>(acc, red, t)) {
            float2* S = ws + 16384 + (x << 2);
            S[0] = make_float2(0.5f * (acc[6] + acc[0]),  0.5f * acc[1]);              // e0
            S[1] = make_float2(0.5f * (acc[6] - acc[0]), -0.5f * acc[1]);              // e1
            S[2] = make_float2(0.5f * (acc[4] + acc[2]),  0.5f * (acc[5] + acc[3]));   // f0
            S[3] = make_float2(0.5f * (acc[4] - acc[2]),  0.5f * (acc[5] - acc[3]));   // f1
        }
    }
}

// ---------------- K2: per (evolution, row-quarter): T, R = LA*T*LA^H -> out ----------------
template <int OM>
__global__ __launch_bounds__(512) void qk2(const float* __restrict__ w, const float2* __restrict__ ws,
                                           void* __restrict__ outv) {
    __shared__ float2 LAH[4096];
    __shared__ float2 A1s[4096];
    __shared__ float2 Ts[4096];
    __shared__ float2 Us[1024];
    __shared__ float2 G6[6][2][2];

    const int bx = blockIdx.x;
    const int ev = bx >> 2, rq = bx & 3;
    const int order = ev >> 1, b = ev & 1;
    const int x1 = order ? 2 + b : b;       // LA-side input
    const int x2 = order ? b : 2 + b;       // LB-side (traced) input
    const int t = threadIdx.x;

    if (t < 6) make_G(w, t, G6[t]);
    __syncthreads();
    build_LH(G6, LAH, t, 512);
    for (int e = t; e < 4096; e += 512) A1s[e] = ws[(x1 << 12) + e];
    __syncthreads();

    const float2 e0 = ws[16384 + (x2 << 2) + 0];
    const float2 e1 = ws[16384 + (x2 << 2) + 1];
    const float2 f0 = ws[16384 + (x2 << 2) + 2];
    const float2 f1 = ws[16384 + (x2 << 2) + 3];

    for (int idx = t; idx < 4096; idx += 512) {
        int p = idx >> 6, q = idx & 63;
        int u = p ^ (p >> 1), v = q ^ (q >> 1);
        float2 c0, c1;
        pick_cc(p, q, e0, e1, f0, f1, c0, c1);
        float2 a  = A1s[(u << 6) + v];
        float2 a2 = A1s[((u ^ 48) << 6) + (v ^ 48)];
        Ts[idx] = cadd(cmul(a, c0), cmul(a2, c1));
    }
    __syncthreads();

    const int tr = t >> 5, tc = t & 31;
    const int i = (rq << 4) + tr;
    float2 u0 = make_float2(0, 0), u1 = make_float2(0, 0);
    #pragma unroll 16
    for (int k = 0; k < 64; ++k) {
        float2 la = LAH[(k << 6) + i];              // conj(LA[i][k]), broadcast
        u0 = cfmac(la, Ts[(k << 6) + tc], u0);
        u1 = cfmac(la, Ts[(k << 6) + tc + 32], u1);
    }
    Us[(tr << 6) + tc] = u0; Us[(tr << 6) + tc + 32] = u1;
    __syncthreads();
    float2 r0 = make_float2(0, 0), r1 = make_float2(0, 0);
    #pragma unroll 16
    for (int k = 0; k < 64; ++k) {
        float2 uu = Us[(tr << 6) + k];              // broadcast
        r0 = cfma(uu, LAH[(k << 6) + tc], r0);
        r1 = cfma(uu, LAH[(k << 6) + tc + 32], r1);
    }
    write_out<OM>(outv, ev, i, tc, r0, r1);
}

// ---------------- Mono fallback: 4 blocks x 1024, everything in one block ----------------
template <int OM>
__global__ __launch_bounds__(1024) void qmono(const float* __restrict__ A, const float* __restrict__ B,
                                              const float* __restrict__ w, void* __restrict__ outv) {
    __shared__ float2 LAH[4096];
    __shared__ float  Xr[4096];
    __shared__ float2 BA[4096];
    __shared__ float2 BB[4096];
    __shared__ float2 G6[6][2][2];
    __shared__ float  red[16][8];
    __shared__ float2 Sq[4];

    const int ev = blockIdx.x;
    const int order = ev >> 1, b = ev & 1;
    const int t = threadIdx.x;
    const float* X1g = (order ? B : A) + b * 4096;
    const float* X2g = (order ? A : B) + b * 4096;

    if (t < 6) make_G(w, t, G6[t]);
    __syncthreads();
    build_LH(G6, LAH, t, 1024);
    for (int e = t; e < 4096; e += 1024) Xr[e] = X1g[e];
    __syncthreads();

    const int tr = t >> 5, tc = t & 31;
    const int i0 = tr, i1 = tr + 32;
    {   // GEMM1: BA = LA @ X1
        float2 a00 = {0,0}, a01 = {0,0}, a10 = {0,0}, a11 = {0,0};
        #pragma unroll 16
        for (int k = 0; k < 64; ++k) {
            float2 la0 = LAH[(k << 6) + i0], la1 = LAH[(k << 6) + i1];
            float x0 = Xr[(k << 6) + tc], x1 = Xr[(k << 6) + tc + 32];
            a00.x = fmaf(la0.x, x0, a00.x); a00.y = fmaf(-la0.y, x0, a00.y);
            a01.x = fmaf(la0.x, x1, a01.x); a01.y = fmaf(-la0.y, x1, a01.y);
            a10.x = fmaf(la1.x, x0, a10.x); a10.y = fmaf(-la1.y, x0, a10.y);
            a11.x = fmaf(la1.x, x1, a11.x); a11.y = fmaf(-la1.y, x1, a11.y);
        }
        BA[(i0 << 6) + tc] = a00; BA[(i0 << 6) + tc + 32] = a01;
        BA[(i1 << 6) + tc] = a10; BA[(i1 << 6) + tc + 32] = a11;
    }
    __syncthreads();
    {   // GEMM2: BB = A1 = BA @ LAH
        float2 a00 = {0,0}, a01 = {0,0}, a10 = {0,0}, a11 = {0,0};
        #pragma unroll 16
        for (int k = 0; k < 64; ++k) {
            float2 t0 = BA[(i0 << 6) + k], t1 = BA[(i1 << 6) + k];
            float2 l0 = LAH[(k << 6) + tc], l1 = LAH[(k << 6) + tc + 32];
            a00 = cfma(t0, l0, a00); a01 = cfma(t0, l1, a01);
            a10 = cfma(t1, l0, a10); a11 = cfma(t1, l1, a11);
        }
        BB[(i0 << 6) + tc] = a00; BB[(i0 << 6) + tc + 32] = a01;
        BB[(i1 << 6) + tc] = a10; BB[(i1 << 6) + tc + 32] = a11;
    }
    __syncthreads();
    for (int e = t; e < 4096; e += 1024) Xr[e] = X2g[e];
    if (t < 6) make_G(w, 6 + t, G6[t]);     // LAH stays; only G6 reused
    __syncthreads();
    {   // traces -> Sq
        float2 zt[6][2][2], x6[2][2], xz6[2][2];
        make_tables(G6, zt, x6, xz6);
        float acc[7] = {0, 0, 0, 0, 0, 0, 0};
        trace_acc(Xr, zt, x6, xz6, t, 1024, acc);
        if (reduce7<1024>(acc, red, t)) {
            Sq[0] = make_float2(0.5f * (acc[6] + acc[0]),  0.5f * acc[1]);
            Sq[1] = make_float2(0.5f * (acc[6] - acc[0]), -0.5f * acc[1]);
            Sq[2] = make_float2(0.5f * (acc[4] + acc[2]),  0.5f * (acc[5] + acc[3]));
            Sq[3] = make_float2(0.5f * (acc[4] - acc[2]),  0.5f * (acc[5] - acc[3]));
        }
    }
    __syncthreads();
    const float2 e0 = Sq[0], e1 = Sq[1], f0 = Sq[2], f1 = Sq[3];
    for (int idx = t; idx < 4096; idx += 1024) {   // T -> BA (reads BB = A1)
        int p = idx >> 6, q = idx & 63;
        int u = p ^ (p >> 1), v = q ^ (q >> 1);
        float2 c0, c1;
        pick_cc(p, q, e0, e1, f0, f1, c0, c1);
        float2 a  = BB[(u << 6) + v];
        float2 a2 = BB[((u ^ 48) << 6) + (v ^ 48)];
        BA[idx] = cadd(cmul(a, c0), cmul(a2, c1));
    }
    __syncthreads();
    {   // GEMM3: BB = U = LA @ T
        float2 a00 = {0,0}, a01 = {0,0}, a10 = {0,0}, a11 = {0,0};
        #pragma unroll 16
        for (int k = 0; k < 64; ++k) {
            float2 la0 = LAH[(k << 6) + i0], la1 = LAH[(k << 6) + i1];
            float2 t0 = BA[(k << 6) + tc], t1 = BA[(k << 6) + tc + 32];
            a00 = cfmac(la0, t0, a00); a01 = cfmac(la0, t1, a01);
            a10 = cfmac(la1, t0, a10); a11 = cfmac(la1, t1, a11);
        }
        __syncthreads();
        BB[(i0 << 6) + tc] = a00; BB[(i0 << 6) + tc + 32] = a01;
        BB[(i1 << 6) + tc] = a10; BB[(i1 << 6) + tc + 32] = a11;
    }
    __syncthreads();
    {   // GEMM4: R = U @ LAH -> out
        float2 a00 = {0,0}, a01 = {0,0}, a10 = {0,0}, a11 = {0,0};
        #pragma unroll 16
        for (int k = 0; k < 64; ++k) {
            float2 u0 = BB[(i0 << 6) + k], u1 = BB[(i1 << 6) + k];
            float2 l0 = LAH[(k << 6) + tc], l1 = LAH[(k << 6) + tc + 32];
            a00 = cfma(u0, l0, a00); a01 = cfma(u0, l1, a01);
            a10 = cfma(u1, l0, a10); a11 = cfma(u1, l1, a11);
        }
        write_out<OM>(outv, ev, i0, tc, a00, a01);
        write_out<OM>(outv, ev, i1, tc, a10, a11);
    }
}

extern "C" void kernel_launch(void* const* d_in, const int* in_sizes, int n_in,
                              void* d_out, int out_size, void* d_ws, size_t ws_size,
                              hipStream_t stream) {
    const float* A = (const float*)d_in[0];   // (2,64,64) f32
    const float* B = (const float*)d_in[1];   // (2,64,64) f32
    const float* w = (const float*)d_in[2];   // (72,) f32
    (void)in_sizes; (void)n_in;
    const bool two = (ws_size >= 16400u * sizeof(float2));   // 131200 B
    if (two) {
        qk1<<<20, 512, 0, stream>>>(A, B, w, (float2*)d_ws);
        if (out_size == 16384)      qk2<0><<<16, 512, 0, stream>>>(w, (const float2*)d_ws, d_out);
        else if (out_size == 32768) qk2<1><<<16, 512, 0, stream>>>(w, (const float2*)d_ws, d_out);
        else                        qk2<2><<<16, 512, 0, stream>>>(w, (const float2*)d_ws, d_out);
    } else {
        if (out_size == 16384)      qmono<0><<<4, 1024, 0, stream>>>(A, B, w, d_out);
        else if (out_size == 32768) qmono<1><<<4, 1024, 0, stream>>>(A, B, w, d_out);
        else                        qmono<2><<<4, 1024, 0, stream>>>(A, B, w, d_out);
    }
}